// Round 1
// baseline (327.363 us; speedup 1.0000x reference)
//
#include <hip/hip_runtime.h>
#include <cmath>

#define NPIX 16384
#define NATOM 1024
#define DIM 64
#define SPAR 8

// ---------------------------------------------------------------------------
// G = D^T D + 1e-4 I   (fp64 accumulate, fp32 store; row k1 per block)
// ---------------------------------------------------------------------------
__global__ __launch_bounds__(256) void k_gram(const float* __restrict__ D,
                                              float* __restrict__ G) {
  int k1 = blockIdx.x;
  __shared__ float d1[DIM];
  if (threadIdx.x < DIM) d1[threadIdx.x] = D[(size_t)threadIdx.x * NATOM + k1];
  __syncthreads();
  for (int k2 = threadIdx.x; k2 < NATOM; k2 += 256) {
    double acc = 0.0;
#pragma unroll
    for (int d = 0; d < DIM; ++d)
      acc += (double)d1[d] * (double)D[(size_t)d * NATOM + k2];
    float g = (float)acc;
    if (k2 == k1) g += 1e-4f;
    G[(size_t)k1 * NATOM + k2] = g;
  }
}

// ---------------------------------------------------------------------------
// HB[n][k] = sum_d D[d][k] * X[d][n]   (fp64 accumulate, fp32 store)
// tile: 128 n x 64 k per block of 256 threads
// ---------------------------------------------------------------------------
__global__ __launch_bounds__(256) void k_hbar(const float* __restrict__ X,
                                              const float* __restrict__ D,
                                              float* __restrict__ HB) {
  __shared__ float sX[DIM][128 + 1];
  __shared__ float sD[DIM][64 + 1];
  int n0 = blockIdx.x * 128, k0 = blockIdx.y * 64;
  for (int i = threadIdx.x; i < DIM * 128; i += 256) {
    int d = i >> 7, nn = i & 127;
    sX[d][nn] = X[(size_t)d * NPIX + n0 + nn];
  }
  for (int i = threadIdx.x; i < DIM * 64; i += 256) {
    int d = i >> 6, kk = i & 63;
    sD[d][kk] = D[(size_t)d * NATOM + k0 + kk];
  }
  __syncthreads();
  int kl = (threadIdx.x & 15) * 4;
  int nl = (threadIdx.x >> 4) * 8;
  double acc[8][4];
#pragma unroll
  for (int i = 0; i < 8; ++i)
#pragma unroll
    for (int j = 0; j < 4; ++j) acc[i][j] = 0.0;
#pragma unroll 4
  for (int d = 0; d < DIM; ++d) {
    float xv[8], dv[4];
#pragma unroll
    for (int i = 0; i < 8; ++i) xv[i] = sX[d][nl + i];
#pragma unroll
    for (int j = 0; j < 4; ++j) dv[j] = sD[d][kl + j];
#pragma unroll
    for (int i = 0; i < 8; ++i)
#pragma unroll
      for (int j = 0; j < 4; ++j) acc[i][j] += (double)xv[i] * (double)dv[j];
  }
#pragma unroll
  for (int i = 0; i < 8; ++i)
#pragma unroll
    for (int j = 0; j < 4; ++j)
      HB[(size_t)(n0 + nl + i) * NATOM + k0 + kl + j] = (float)acc[i][j];
}

// ---------------------------------------------------------------------------
// Batched OMP: one 64-lane wave per pixel. Lane owns k = j*64+lane, j=0..15.
// All small per-pixel state (L, y, coeffs, selected idx) lives in registers,
// replicated across lanes, indexed only by compile-time constants (loops
// fully unrolled). fp64 everywhere downstream of the fp32 G / h_bar values.
// ---------------------------------------------------------------------------
template <bool HBWS>
__global__ __launch_bounds__(256) void k_omp(const float* __restrict__ HB,
                                             const float* __restrict__ X,
                                             const float* __restrict__ D,
                                             const float* __restrict__ G,
                                             float* __restrict__ out) {
  const int lane = threadIdx.x & 63;
  const int n = blockIdx.x * 4 + (threadIdx.x >> 6);

  float hb[16];
  if (HBWS) {
#pragma unroll
    for (int j = 0; j < 16; ++j) hb[j] = HB[(size_t)n * NATOM + j * 64 + lane];
  } else {
    double a[16];
#pragma unroll
    for (int j = 0; j < 16; ++j) a[j] = 0.0;
    for (int d = 0; d < DIM; ++d) {
      float xd = X[(size_t)d * NPIX + n];
#pragma unroll
      for (int j = 0; j < 16; ++j)
        a[j] += (double)xd * (double)D[(size_t)d * NATOM + j * 64 + lane];
    }
#pragma unroll
    for (int j = 0; j < 16; ++j) hb[j] = (float)a[j];
  }

  unsigned mask = 0;  // bit j: atom (j*64+lane) already selected
  int selI[SPAR];
  double Lm[SPAR][SPAR], invL[SPAR], ysel[SPAR], coef[SPAR], hbsel[SPAR];

#pragma unroll 8
  for (int s = 0; s < SPAR; ++s) {
    // ---- h = hb - sum_i coef[i] * G[selI[i], :] ; masked argmax of |h| ----
    double bestv = -2.0;
    int bestk = 0;
#pragma unroll
    for (int j = 0; j < 16; ++j) {
      double beta = 0.0;
#pragma unroll
      for (int i = 0; i < s; ++i)
        beta += coef[i] * (double)G[(size_t)selI[i] * NATOM + j * 64 + lane];
      double h = (double)hb[j] - beta;
      double sc = ((mask >> j) & 1u) ? -1.0 : fabs(h);
      if (sc > bestv) { bestv = sc; bestk = j * 64 + lane; }  // first-occurrence in-lane
    }
    // cross-lane all-reduce argmax, min-index tie-break (matches np.argmax)
#pragma unroll
    for (int off = 32; off; off >>= 1) {
      double ov = __shfl_xor(bestv, off);
      int ok = __shfl_xor(bestk, off);
      if (ov > bestv || (ov == bestv && ok < bestk)) { bestv = ov; bestk = ok; }
    }
    selI[s] = bestk;
    int bj = bestk >> 6, bl = bestk & 63;
    if (lane == bl) mask |= (1u << bj);
    {  // gather h_bar[bestk] (compile-time-indexed select + shfl)
      float v = 0.f;
#pragma unroll
      for (int j = 0; j < 16; ++j)
        if (j == bj) v = hb[j];
      hbsel[s] = (double)__shfl(v, bl);
    }
    // ---- Cholesky update: L_{s+1} = [[L, 0], [w^T, corner]] ----
    double diag = (double)G[(size_t)bestk * NATOM + bestk];
    double w[SPAR];
    double sq = 0.0;
#pragma unroll
    for (int i = 0; i < s; ++i) {
      double a = (double)G[(size_t)selI[i] * NATOM + bestk];
#pragma unroll
      for (int t = 0; t < i; ++t) a -= Lm[i][t] * w[t];
      w[i] = a * invL[i];
      sq += w[i] * w[i];
      Lm[s][i] = w[i];
    }
    double cc = diag - sq;
    if (cc < 1e-6) cc = 1e-6;  // jnp.clip(..., CHOL_EPS)
    Lm[s][s] = sqrt(cc);
    invL[s] = 1.0 / Lm[s][s];
    // ---- solve L y = hb_I ; L^T x = y ----
#pragma unroll
    for (int i = 0; i <= s; ++i) {
      double a = hbsel[i];
#pragma unroll
      for (int t = 0; t < i; ++t) a -= Lm[i][t] * ysel[t];
      ysel[i] = a * invL[i];
    }
#pragma unroll
    for (int i = s; i >= 0; --i) {
      double a = ysel[i];
#pragma unroll
      for (int t = i + 1; t <= s; ++t) a -= Lm[t][i] * coef[t];
      coef[i] = a * invL[i];
    }
  }

  // ---- outputs: recon [n][64], I [n][8], coeffs [n][8] ----
  double r = 0.0;
#pragma unroll
  for (int i = 0; i < SPAR; ++i)
    r += coef[i] * (double)D[(size_t)lane * NATOM + selI[i]];
  out[(size_t)n * DIM + lane] = (float)r;

  float fi = 0.f, fc = 0.f;
#pragma unroll
  for (int i = 0; i < SPAR; ++i)
    if (lane == i) { fi = (float)selI[i]; fc = (float)coef[i]; }
  if (lane < SPAR) {
    out[(size_t)NPIX * DIM + (size_t)n * SPAR + lane] = fi;
    out[(size_t)NPIX * DIM + (size_t)NPIX * SPAR + (size_t)n * SPAR + lane] = fc;
  }
}

extern "C" void kernel_launch(void* const* d_in, const int* in_sizes, int n_in,
                              void* d_out, int out_size, void* d_ws,
                              size_t ws_size, hipStream_t stream) {
  const float* X = (const float*)d_in[0];  // [64, 16384]
  const float* D = (const float*)d_in[1];  // [64, 1024]
  float* out = (float*)d_out;              // [recon | I | coeffs] as fp32
  float* G = (float*)d_ws;
  const size_t needG = (size_t)NATOM * NATOM * sizeof(float);
  const size_t needHB = needG + (size_t)NPIX * NATOM * sizeof(float);

  k_gram<<<dim3(NATOM), dim3(256), 0, stream>>>(D, G);

  if (ws_size >= needHB) {
    float* HB = G + (size_t)NATOM * NATOM;
    k_hbar<<<dim3(NPIX / 128, NATOM / 64), dim3(256), 0, stream>>>(X, D, HB);
    k_omp<true><<<dim3(NPIX / 4), dim3(256), 0, stream>>>(HB, X, D, G, out);
  } else {
    k_omp<false><<<dim3(NPIX / 4), dim3(256), 0, stream>>>(nullptr, X, D, G, out);
  }
}

// Round 2
// 227.139 us; speedup vs baseline: 1.4412x; 1.4412x over previous
//
#include <hip/hip_runtime.h>
#include <cmath>

#define NPIX 16384
#define NATOM 1024
#define DIM 64
#define SPAR 8

// ---------------------------------------------------------------------------
// G = D^T D + 1e-4 I   (fp64 accumulate, fp32 store; row k1 per block)
// ---------------------------------------------------------------------------
__global__ __launch_bounds__(256) void k_gram(const float* __restrict__ D,
                                              float* __restrict__ G) {
  int k1 = blockIdx.x;
  __shared__ float d1[DIM];
  if (threadIdx.x < DIM) d1[threadIdx.x] = D[(size_t)threadIdx.x * NATOM + k1];
  __syncthreads();
  for (int k2 = threadIdx.x; k2 < NATOM; k2 += 256) {
    double acc = 0.0;
#pragma unroll
    for (int d = 0; d < DIM; ++d)
      acc += (double)d1[d] * (double)D[(size_t)d * NATOM + k2];
    float g = (float)acc;
    if (k2 == k1) g += 1e-4f;
    G[(size_t)k1 * NATOM + k2] = g;
  }
}

// ---------------------------------------------------------------------------
// HB[n][k] = sum_d D[d][k] * X[d][n]   (fp64 accumulate, fp32 store)
// ---------------------------------------------------------------------------
__global__ __launch_bounds__(256) void k_hbar(const float* __restrict__ X,
                                              const float* __restrict__ D,
                                              float* __restrict__ HB) {
  __shared__ float sX[DIM][128 + 1];
  __shared__ float sD[DIM][64 + 1];
  int n0 = blockIdx.x * 128, k0 = blockIdx.y * 64;
  for (int i = threadIdx.x; i < DIM * 128; i += 256) {
    int d = i >> 7, nn = i & 127;
    sX[d][nn] = X[(size_t)d * NPIX + n0 + nn];
  }
  for (int i = threadIdx.x; i < DIM * 64; i += 256) {
    int d = i >> 6, kk = i & 63;
    sD[d][kk] = D[(size_t)d * NATOM + k0 + kk];
  }
  __syncthreads();
  int kl = (threadIdx.x & 15) * 4;
  int nl = (threadIdx.x >> 4) * 8;
  double acc[8][4];
#pragma unroll
  for (int i = 0; i < 8; ++i)
#pragma unroll
    for (int j = 0; j < 4; ++j) acc[i][j] = 0.0;
#pragma unroll 4
  for (int d = 0; d < DIM; ++d) {
    float xv[8], dv[4];
#pragma unroll
    for (int i = 0; i < 8; ++i) xv[i] = sX[d][nl + i];
#pragma unroll
    for (int j = 0; j < 4; ++j) dv[j] = sD[d][kl + j];
#pragma unroll
    for (int i = 0; i < 8; ++i)
#pragma unroll
      for (int j = 0; j < 4; ++j) acc[i][j] += (double)xv[i] * (double)dv[j];
  }
#pragma unroll
  for (int i = 0; i < 8; ++i)
#pragma unroll
    for (int j = 0; j < 4; ++j)
      HB[(size_t)(n0 + nl + i) * NATOM + k0 + kl + j] = (float)acc[i][j];
}

// ---------------------------------------------------------------------------
// Batched OMP: one 64-lane wave per pixel. Lane owns k = j*64+lane, j=0..15.
// Full fp32 core (matches the reference's precision class). selI is
// readfirstlane'd -> SGPR row bases for all G loads. y is updated
// incrementally (forward-solve entries are stable as L grows). The newly
// selected row segment is prefetched into registers so its L2 latency
// overlaps the serial Cholesky/solve chain.
// ---------------------------------------------------------------------------
template <bool HBWS>
__global__ __launch_bounds__(256) void k_omp(const float* __restrict__ HB,
                                             const float* __restrict__ X,
                                             const float* __restrict__ D,
                                             const float* __restrict__ G,
                                             float* __restrict__ out) {
  const int lane = threadIdx.x & 63;
  const int n = blockIdx.x * 4 + (threadIdx.x >> 6);

  float hb[16];
  if (HBWS) {
#pragma unroll
    for (int j = 0; j < 16; ++j) hb[j] = HB[(size_t)n * NATOM + j * 64 + lane];
  } else {
    double a[16];
#pragma unroll
    for (int j = 0; j < 16; ++j) a[j] = 0.0;
    for (int d = 0; d < DIM; ++d) {
      float xd = X[(size_t)d * NPIX + n];
#pragma unroll
      for (int j = 0; j < 16; ++j)
        a[j] += (double)xd * (double)D[(size_t)d * NATOM + j * 64 + lane];
    }
#pragma unroll
    for (int j = 0; j < 16; ++j) hb[j] = (float)a[j];
  }

  unsigned mask = 0;  // bit j: atom (j*64+lane) already selected
  int selI[SPAR];
  float Lm[SPAR][SPAR], invL[SPAR], ysel[SPAR], coefF[SPAR];
  float lastrow[16];  // G[selI[s-1]][j*64+lane], prefetched at selection time

#pragma unroll 8
  for (int s = 0; s < SPAR; ++s) {
    // ---- h = hb - sum_i coef[i] * G[selI[i], :] ; masked argmax of |h| ----
    float h[16];
#pragma unroll
    for (int j = 0; j < 16; ++j) h[j] = hb[j];
#pragma unroll
    for (int i = 0; i < s; ++i) {
      float c = coefF[i];
      if (i == s - 1) {
#pragma unroll
        for (int j = 0; j < 16; ++j) h[j] = fmaf(-c, lastrow[j], h[j]);
      } else {
        const float* __restrict__ row = G + (size_t)selI[i] * NATOM;
#pragma unroll
        for (int j = 0; j < 16; ++j) h[j] = fmaf(-c, row[j * 64 + lane], h[j]);
      }
    }
    float bestv = -2.0f;
    int bestk = 0;
#pragma unroll
    for (int j = 0; j < 16; ++j) {
      float sc = ((mask >> j) & 1u) ? -1.0f : fabsf(h[j]);
      if (sc > bestv) { bestv = sc; bestk = j * 64 + lane; }  // first-occurrence in-lane
    }
    // cross-lane all-reduce argmax, min-index tie-break (matches np.argmax)
#pragma unroll
    for (int off = 32; off; off >>= 1) {
      float ov = __shfl_xor(bestv, off);
      int ok = __shfl_xor(bestk, off);
      if (ov > bestv || (ov == bestv && ok < bestk)) { bestv = ov; bestk = ok; }
    }
    const int bk = __builtin_amdgcn_readfirstlane(bestk);  // wave-uniform -> SGPR
    selI[s] = bk;
    const int bj = bk >> 6, bl = bk & 63;
    if (lane == bl) mask |= (1u << bj);

    // gather h_bar[bk] (compile-time-indexed select + shfl)
    float v = 0.f;
#pragma unroll
    for (int j = 0; j < 16; ++j)
      if (j == bj) v = hb[j];
    const float hbs = __shfl(v, bl);

    // prefetch new row segment; latency overlaps the serial chol/solve below
#pragma unroll
    for (int j = 0; j < 16; ++j)
      lastrow[j] = G[(size_t)bk * NATOM + j * 64 + lane];

    // ---- Cholesky update: L_{s+1} = [[L, 0], [w^T, corner]] ----
    const float diag = G[(size_t)bk * NATOM + bk];
    float w[SPAR];
    float sq = 0.f;
#pragma unroll
    for (int i = 0; i < s; ++i) {
      float a = G[(size_t)selI[i] * NATOM + bk];
#pragma unroll
      for (int t = 0; t < i; ++t) a = fmaf(-Lm[i][t], w[t], a);
      w[i] = a * invL[i];
      sq += w[i] * w[i];
      Lm[s][i] = w[i];
    }
    float cc = diag - sq;
    if (cc < 1e-6f) cc = 1e-6f;  // jnp.clip(..., CHOL_EPS)
    Lm[s][s] = sqrtf(cc);
    invL[s] = 1.0f / Lm[s][s];

    // ---- y_s (incremental forward solve; earlier entries are stable) ----
    {
      float a = hbs;
#pragma unroll
      for (int t = 0; t < s; ++t) a = fmaf(-Lm[s][t], ysel[t], a);
      ysel[s] = a * invL[s];
    }
    // ---- coef: backward solve L^T x = y (fresh each step, as reference) ----
#pragma unroll
    for (int i = s; i >= 0; --i) {
      float a = ysel[i];
#pragma unroll
      for (int t = i + 1; t <= s; ++t) a = fmaf(-Lm[t][i], coefF[t], a);
      coefF[i] = a * invL[i];
    }
  }

  // ---- outputs: recon [n][64], I [n][8], coeffs [n][8] ----
  double r = 0.0;
#pragma unroll
  for (int i = 0; i < SPAR; ++i)
    r += (double)coefF[i] * (double)D[(size_t)lane * NATOM + selI[i]];
  out[(size_t)n * DIM + lane] = (float)r;

  float fi = 0.f, fc = 0.f;
#pragma unroll
  for (int i = 0; i < SPAR; ++i)
    if (lane == i) { fi = (float)selI[i]; fc = coefF[i]; }
  if (lane < SPAR) {
    out[(size_t)NPIX * DIM + (size_t)n * SPAR + lane] = fi;
    out[(size_t)NPIX * DIM + (size_t)NPIX * SPAR + (size_t)n * SPAR + lane] = fc;
  }
}

extern "C" void kernel_launch(void* const* d_in, const int* in_sizes, int n_in,
                              void* d_out, int out_size, void* d_ws,
                              size_t ws_size, hipStream_t stream) {
  const float* X = (const float*)d_in[0];  // [64, 16384]
  const float* D = (const float*)d_in[1];  // [64, 1024]
  float* out = (float*)d_out;              // [recon | I | coeffs] as fp32
  float* G = (float*)d_ws;
  const size_t needG = (size_t)NATOM * NATOM * sizeof(float);
  const size_t needHB = needG + (size_t)NPIX * NATOM * sizeof(float);

  k_gram<<<dim3(NATOM), dim3(256), 0, stream>>>(D, G);

  if (ws_size >= needHB) {
    float* HB = G + (size_t)NATOM * NATOM;
    k_hbar<<<dim3(NPIX / 128, NATOM / 64), dim3(256), 0, stream>>>(X, D, HB);
    k_omp<true><<<dim3(NPIX / 4), dim3(256), 0, stream>>>(HB, X, D, G, out);
  } else {
    k_omp<false><<<dim3(NPIX / 4), dim3(256), 0, stream>>>(nullptr, X, D, G, out);
  }
}

// Round 3
// 202.597 us; speedup vs baseline: 1.6158x; 1.1211x over previous
//
#include <hip/hip_runtime.h>
#include <cmath>

#define NPIX 16384
#define NATOM 1024
#define DIM 64
#define SPAR 8

// ---------------------------------------------------------------------------
// G = D^T D + 1e-4 I   (fp64 accumulate, fp32 store; row k1 per block)
// Tiny (67M MAC) — precision kept maximal since G feeds every downstream op.
// ---------------------------------------------------------------------------
__global__ __launch_bounds__(256) void k_gram(const float* __restrict__ D,
                                              float* __restrict__ G) {
  int k1 = blockIdx.x;
  __shared__ float d1[DIM];
  if (threadIdx.x < DIM) d1[threadIdx.x] = D[(size_t)threadIdx.x * NATOM + k1];
  __syncthreads();
  for (int k2 = threadIdx.x; k2 < NATOM; k2 += 256) {
    double acc = 0.0;
#pragma unroll
    for (int d = 0; d < DIM; ++d)
      acc += (double)d1[d] * (double)D[(size_t)d * NATOM + k2];
    float g = (float)acc;
    if (k2 == k1) g += 1e-4f;
    G[(size_t)k1 * NATOM + k2] = g;
  }
}

// ---------------------------------------------------------------------------
// HB[n][k] = sum_d D[d][k] * X[d][n]  — fp32, 128n x 128k tile, 8x8/thread.
// fp32 accumulation matches the reference's own precision class (np sgemm).
// ---------------------------------------------------------------------------
__global__ __launch_bounds__(256) void k_hbar(const float* __restrict__ X,
                                              const float* __restrict__ D,
                                              float* __restrict__ HB) {
  __shared__ float sX[DIM][128];
  __shared__ float sD[DIM][128];
  const int n0 = blockIdx.x * 128, k0 = blockIdx.y * 128;
  for (int i = threadIdx.x; i < DIM * 32; i += 256) {
    int d = i >> 5, c4 = (i & 31) * 4;
    *reinterpret_cast<float4*>(&sX[d][c4]) =
        *reinterpret_cast<const float4*>(&X[(size_t)d * NPIX + n0 + c4]);
    *reinterpret_cast<float4*>(&sD[d][c4]) =
        *reinterpret_cast<const float4*>(&D[(size_t)d * NATOM + k0 + c4]);
  }
  __syncthreads();
  const int nl = (threadIdx.x & 15) * 8;
  const int kl = (threadIdx.x >> 4) * 8;
  float acc[8][8];
#pragma unroll
  for (int i = 0; i < 8; ++i)
#pragma unroll
    for (int j = 0; j < 8; ++j) acc[i][j] = 0.f;
#pragma unroll 4
  for (int d = 0; d < DIM; ++d) {
    float xv[8], dv[8];
    *reinterpret_cast<float4*>(&xv[0]) = *reinterpret_cast<float4*>(&sX[d][nl]);
    *reinterpret_cast<float4*>(&xv[4]) = *reinterpret_cast<float4*>(&sX[d][nl + 4]);
    *reinterpret_cast<float4*>(&dv[0]) = *reinterpret_cast<float4*>(&sD[d][kl]);
    *reinterpret_cast<float4*>(&dv[4]) = *reinterpret_cast<float4*>(&sD[d][kl + 4]);
#pragma unroll
    for (int i = 0; i < 8; ++i)
#pragma unroll
      for (int j = 0; j < 8; ++j) acc[i][j] = fmaf(xv[i], dv[j], acc[i][j]);
  }
#pragma unroll
  for (int i = 0; i < 8; ++i) {
#pragma unroll
    for (int j = 0; j < 2; ++j)
      *reinterpret_cast<float4*>(
          &HB[(size_t)(n0 + nl + i) * NATOM + k0 + kl + j * 4]) =
          *reinterpret_cast<float4*>(&acc[i][j * 4]);
  }
}

// ---------------------------------------------------------------------------
// Batched OMP: one 64-lane wave per pixel. Lane owns k = j*64+lane, j=0..15.
// All selected G rows are kept in registers (rows[8][16]) — the beta/argmax
// loop is pure-register FMA, numerically identical (same fp32 values, same
// order) to re-reading G. Cholesky column/diag loads are wave-uniform
// (scalar). selI is readfirstlane'd so all addressing is SGPR-based.
// ---------------------------------------------------------------------------
template <bool HBWS>
__global__ __launch_bounds__(256) void k_omp(const float* __restrict__ HB,
                                             const float* __restrict__ X,
                                             const float* __restrict__ D,
                                             const float* __restrict__ G,
                                             float* __restrict__ out) {
  const int lane = threadIdx.x & 63;
  const int n = blockIdx.x * 4 + (threadIdx.x >> 6);

  float hb[16];
  if (HBWS) {
#pragma unroll
    for (int j = 0; j < 16; ++j) hb[j] = HB[(size_t)n * NATOM + j * 64 + lane];
  } else {
    double a[16];
#pragma unroll
    for (int j = 0; j < 16; ++j) a[j] = 0.0;
    for (int d = 0; d < DIM; ++d) {
      float xd = X[(size_t)d * NPIX + n];
#pragma unroll
      for (int j = 0; j < 16; ++j)
        a[j] += (double)xd * (double)D[(size_t)d * NATOM + j * 64 + lane];
    }
#pragma unroll
    for (int j = 0; j < 16; ++j) hb[j] = (float)a[j];
  }

  unsigned mask = 0;  // bit j: atom (j*64+lane) already selected
  int selI[SPAR];
  float rows[SPAR][16];  // rows[i][j] = G[selI[i]][j*64+lane]
  float Lm[SPAR][SPAR], invL[SPAR], ysel[SPAR], coefF[SPAR];

#pragma unroll 8
  for (int s = 0; s < SPAR; ++s) {
    // ---- h_j = hb_j - sum_i coef[i]*rows[i][j]; masked argmax of |h| ----
    float bestv = -2.0f;
    int bestk = 0;
#pragma unroll
    for (int j = 0; j < 16; ++j) {
      float h = hb[j];
#pragma unroll
      for (int i = 0; i < SPAR; ++i)
        if (i < s) h = fmaf(-coefF[i], rows[i][j], h);
      float sc = ((mask >> j) & 1u) ? -1.0f : fabsf(h);
      if (sc > bestv) { bestv = sc; bestk = j * 64 + lane; }  // first-occurrence
    }
    // cross-lane all-reduce argmax, min-index tie-break (matches np.argmax)
#pragma unroll
    for (int off = 32; off; off >>= 1) {
      float ov = __shfl_xor(bestv, off);
      int ok = __shfl_xor(bestk, off);
      if (ov > bestv || (ov == bestv && ok < bestk)) { bestv = ov; bestk = ok; }
    }
    const int bk = __builtin_amdgcn_readfirstlane(bestk);  // wave-uniform
    selI[s] = bk;
    const int bj = bk >> 6, bl = bk & 63;
    if (lane == bl) mask |= (1u << bj);

    // gather h_bar[bk] (compile-time-indexed select + shfl)
    float v = 0.f;
#pragma unroll
    for (int j = 0; j < 16; ++j)
      if (j == bj) v = hb[j];
    const float hbs = __shfl(v, bl);

    // fetch new row into registers; latency overlaps chol/solve below
#pragma unroll
    for (int j = 0; j < 16; ++j)
      rows[s][j] = G[(size_t)bk * NATOM + j * 64 + lane];

    // ---- Cholesky update: L_{s+1} = [[L, 0], [w^T, corner]] ----
    const float diag = G[(size_t)bk * NATOM + bk];  // uniform (scalar) load
    float w[SPAR];
    float sq = 0.f;
#pragma unroll
    for (int i = 0; i < SPAR; ++i)
      if (i < s) {
        float a = G[(size_t)selI[i] * NATOM + bk];  // uniform (scalar) load
#pragma unroll
        for (int t = 0; t < SPAR; ++t)
          if (t < i) a = fmaf(-Lm[i][t], w[t], a);
        w[i] = a * invL[i];
        sq += w[i] * w[i];
        Lm[s][i] = w[i];
      }
    float cc = diag - sq;
    if (cc < 1e-6f) cc = 1e-6f;  // jnp.clip(..., CHOL_EPS)
    Lm[s][s] = sqrtf(cc);
    invL[s] = 1.0f / Lm[s][s];

    // ---- y_s (incremental forward solve; earlier entries are stable) ----
    {
      float a = hbs;
#pragma unroll
      for (int t = 0; t < SPAR; ++t)
        if (t < s) a = fmaf(-Lm[s][t], ysel[t], a);
      ysel[s] = a * invL[s];
    }
    // ---- coef: backward solve L^T x = y (fresh each step, as reference) ----
#pragma unroll
    for (int i = SPAR - 1; i >= 0; --i)
      if (i <= s) {
        float a = ysel[i];
#pragma unroll
        for (int t = 0; t < SPAR; ++t)
          if (t > i && t <= s) a = fmaf(-Lm[t][i], coefF[t], a);
        coefF[i] = a * invL[i];
      }
  }

  // ---- outputs: recon [n][64], I [n][8], coeffs [n][8] ----
  double r = 0.0;
#pragma unroll
  for (int i = 0; i < SPAR; ++i)
    r += (double)coefF[i] * (double)D[(size_t)lane * NATOM + selI[i]];
  out[(size_t)n * DIM + lane] = (float)r;

  float fi = 0.f, fc = 0.f;
#pragma unroll
  for (int i = 0; i < SPAR; ++i)
    if (lane == i) { fi = (float)selI[i]; fc = coefF[i]; }
  if (lane < SPAR) {
    out[(size_t)NPIX * DIM + (size_t)n * SPAR + lane] = fi;
    out[(size_t)NPIX * DIM + (size_t)NPIX * SPAR + (size_t)n * SPAR + lane] = fc;
  }
}

extern "C" void kernel_launch(void* const* d_in, const int* in_sizes, int n_in,
                              void* d_out, int out_size, void* d_ws,
                              size_t ws_size, hipStream_t stream) {
  const float* X = (const float*)d_in[0];  // [64, 16384]
  const float* D = (const float*)d_in[1];  // [64, 1024]
  float* out = (float*)d_out;              // [recon | I | coeffs] as fp32
  float* G = (float*)d_ws;
  const size_t needG = (size_t)NATOM * NATOM * sizeof(float);
  const size_t needHB = needG + (size_t)NPIX * NATOM * sizeof(float);

  k_gram<<<dim3(NATOM), dim3(256), 0, stream>>>(D, G);

  if (ws_size >= needHB) {
    float* HB = G + (size_t)NATOM * NATOM;
    k_hbar<<<dim3(NPIX / 128, NATOM / 128), dim3(256), 0, stream>>>(X, D, HB);
    k_omp<true><<<dim3(NPIX / 4), dim3(256), 0, stream>>>(HB, X, D, G, out);
  } else {
    k_omp<false><<<dim3(NPIX / 4), dim3(256), 0, stream>>>(nullptr, X, D, G, out);
  }
}

// Round 4
// 191.280 us; speedup vs baseline: 1.7114x; 1.0592x over previous
//
#include <hip/hip_runtime.h>
#include <cmath>

#define NPIX 16384
#define NATOM 1024
#define DIM 64
#define SPAR 8

// ---------------------------------------------------------------------------
// G = D^T D + 1e-4 I   (fp64 accumulate, fp32 store; row k1 per block)
// ---------------------------------------------------------------------------
__global__ __launch_bounds__(256) void k_gram(const float* __restrict__ D,
                                              float* __restrict__ G) {
  int k1 = blockIdx.x;
  __shared__ float d1[DIM];
  if (threadIdx.x < DIM) d1[threadIdx.x] = D[(size_t)threadIdx.x * NATOM + k1];
  __syncthreads();
  for (int k2 = threadIdx.x; k2 < NATOM; k2 += 256) {
    double acc = 0.0;
#pragma unroll
    for (int d = 0; d < DIM; ++d)
      acc += (double)d1[d] * (double)D[(size_t)d * NATOM + k2];
    float g = (float)acc;
    if (k2 == k1) g += 1e-4f;
    G[(size_t)k1 * NATOM + k2] = g;
  }
}

// ---------------------------------------------------------------------------
// Dt[k][d] = D[d][k]  (256 KB transpose so the recon gather is coalesced)
// ---------------------------------------------------------------------------
__global__ __launch_bounds__(256) void k_tr(const float* __restrict__ D,
                                            float* __restrict__ Dt) {
  int idx = blockIdx.x * 256 + threadIdx.x;  // 65536 = 64*1024
  int d = idx >> 10, k = idx & 1023;
  Dt[(size_t)k * DIM + d] = D[idx];
}

// ---------------------------------------------------------------------------
// HB[n][k] = sum_d D[d][k] * X[d][n]  — fp32, 128n x 128k tile, 8x8/thread.
// ---------------------------------------------------------------------------
__global__ __launch_bounds__(256) void k_hbar(const float* __restrict__ X,
                                              const float* __restrict__ D,
                                              float* __restrict__ HB) {
  __shared__ float sX[DIM][128];
  __shared__ float sD[DIM][128];
  const int n0 = blockIdx.x * 128, k0 = blockIdx.y * 128;
  for (int i = threadIdx.x; i < DIM * 32; i += 256) {
    int d = i >> 5, c4 = (i & 31) * 4;
    *reinterpret_cast<float4*>(&sX[d][c4]) =
        *reinterpret_cast<const float4*>(&X[(size_t)d * NPIX + n0 + c4]);
    *reinterpret_cast<float4*>(&sD[d][c4]) =
        *reinterpret_cast<const float4*>(&D[(size_t)d * NATOM + k0 + c4]);
  }
  __syncthreads();
  const int nl = (threadIdx.x & 15) * 8;
  const int kl = (threadIdx.x >> 4) * 8;
  float acc[8][8];
#pragma unroll
  for (int i = 0; i < 8; ++i)
#pragma unroll
    for (int j = 0; j < 8; ++j) acc[i][j] = 0.f;
#pragma unroll 4
  for (int d = 0; d < DIM; ++d) {
    float xv[8], dv[8];
    *reinterpret_cast<float4*>(&xv[0]) = *reinterpret_cast<float4*>(&sX[d][nl]);
    *reinterpret_cast<float4*>(&xv[4]) = *reinterpret_cast<float4*>(&sX[d][nl + 4]);
    *reinterpret_cast<float4*>(&dv[0]) = *reinterpret_cast<float4*>(&sD[d][kl]);
    *reinterpret_cast<float4*>(&dv[4]) = *reinterpret_cast<float4*>(&sD[d][kl + 4]);
#pragma unroll
    for (int i = 0; i < 8; ++i)
#pragma unroll
      for (int j = 0; j < 8; ++j) acc[i][j] = fmaf(xv[i], dv[j], acc[i][j]);
  }
#pragma unroll
  for (int i = 0; i < 8; ++i) {
#pragma unroll
    for (int j = 0; j < 2; ++j)
      *reinterpret_cast<float4*>(
          &HB[(size_t)(n0 + nl + i) * NATOM + k0 + kl + j * 4]) =
          *reinterpret_cast<float4*>(&acc[i][j * 4]);
  }
}

// ---------------------------------------------------------------------------
// Batched OMP: one 64-lane wave per pixel. Lane owns k = j*64+lane, j=0..15.
// Selected G rows are PINNED in registers via empty-asm keep-alives placed at
// the end of each step (so the vmcnt wait overlaps the chol/solve chain).
// Argmax uses a packed u64 key (|h| bits << 32 | ~k): max with min-index
// tie-break is associative -> depth-4 in-lane tree + 6-step u64 butterfly.
// Numerics (h fmaf order, chol, solves) identical to the passing round-3.
// ---------------------------------------------------------------------------
template <bool HBWS, bool DTW>
__global__ __launch_bounds__(256, 2) void k_omp(const float* __restrict__ HB,
                                                const float* __restrict__ X,
                                                const float* __restrict__ D,
                                                const float* __restrict__ Dt,
                                                const float* __restrict__ G,
                                                float* __restrict__ out) {
  const int lane = threadIdx.x & 63;
  const int n = blockIdx.x * 4 + (threadIdx.x >> 6);

  float hb[16];
  if (HBWS) {
#pragma unroll
    for (int j = 0; j < 16; ++j) hb[j] = HB[(size_t)n * NATOM + j * 64 + lane];
  } else {
    double a[16];
#pragma unroll
    for (int j = 0; j < 16; ++j) a[j] = 0.0;
    for (int d = 0; d < DIM; ++d) {
      float xd = X[(size_t)d * NPIX + n];
#pragma unroll
      for (int j = 0; j < 16; ++j)
        a[j] += (double)xd * (double)D[(size_t)d * NATOM + j * 64 + lane];
    }
#pragma unroll
    for (int j = 0; j < 16; ++j) hb[j] = (float)a[j];
  }
#pragma unroll
  for (int j = 0; j < 16; ++j) asm volatile("" : "+v"(hb[j]));

  unsigned mask = 0;  // bit j: atom (j*64+lane) already selected
  int selI[SPAR];
  float rows[SPAR - 1][16];  // rows[i][j] = G[selI[i]][j*64+lane]
  float Lm[SPAR][SPAR], invL[SPAR], ysel[SPAR], coefF[SPAR];

#pragma unroll 8
  for (int s = 0; s < SPAR; ++s) {
    // ---- h_j = hb_j - sum_i coef[i]*rows[i][j]; packed-key argmax ----
    unsigned long long key[16];
#pragma unroll
    for (int j = 0; j < 16; ++j) {
      float h = hb[j];
#pragma unroll
      for (int i = 0; i < SPAR - 1; ++i)
        if (i < s) h = fmaf(-coefF[i], rows[i][j], h);
      unsigned ub = __float_as_uint(fabsf(h));
      unsigned long long kk =
          ((unsigned long long)ub << 32) | (unsigned)(~(j * 64 + lane));
      key[j] = ((mask >> j) & 1u) ? 0ull : kk;
    }
#pragma unroll
    for (int st = 8; st >= 1; st >>= 1)
#pragma unroll
      for (int j = 0; j < st; ++j)
        key[j] = key[j] >= key[j + st] ? key[j] : key[j + st];
    unsigned long long k0 = key[0];
#pragma unroll
    for (int off = 1; off <= 32; off <<= 1) {
      unsigned long long o = __shfl_xor(k0, off);
      k0 = k0 >= o ? k0 : o;
    }
    const int bestk = (int)(~(unsigned)k0) & (NATOM - 1);
    const int bk = __builtin_amdgcn_readfirstlane(bestk);  // wave-uniform
    selI[s] = bk;
    const int bj = bk >> 6, bl = bk & 63;
    if (lane == bl) mask |= (1u << bj);

    // gather h_bar[bk] (compile-time-indexed select + shfl)
    float v = 0.f;
#pragma unroll
    for (int j = 0; j < 16; ++j)
      if (j == bj) v = hb[j];
    const float hbs = __shfl(v, bl);

    // issue new-row fetch; completes during chol/solve (pin is at step end)
    if (s < SPAR - 1) {
#pragma unroll
      for (int j = 0; j < 16; ++j)
        rows[s][j] = G[(size_t)bk * NATOM + j * 64 + lane];
    }

    // ---- Cholesky update: L_{s+1} = [[L, 0], [w^T, corner]] ----
    const float diag = G[(size_t)bk * NATOM + bk];  // uniform (scalar) load
    float w[SPAR];
    float sq = 0.f;
#pragma unroll
    for (int i = 0; i < SPAR; ++i)
      if (i < s) {
        float a = G[(size_t)selI[i] * NATOM + bk];  // uniform (scalar) load
#pragma unroll
        for (int t = 0; t < SPAR; ++t)
          if (t < i) a = fmaf(-Lm[i][t], w[t], a);
        w[i] = a * invL[i];
        sq += w[i] * w[i];
        Lm[s][i] = w[i];
      }
    float cc = diag - sq;
    if (cc < 1e-6f) cc = 1e-6f;  // jnp.clip(..., CHOL_EPS)
    Lm[s][s] = sqrtf(cc);
    invL[s] = 1.0f / Lm[s][s];

    // ---- y_s (incremental forward solve; earlier entries are stable) ----
    {
      float a = hbs;
#pragma unroll
      for (int t = 0; t < SPAR; ++t)
        if (t < s) a = fmaf(-Lm[s][t], ysel[t], a);
      ysel[s] = a * invL[s];
    }
    // ---- coef: backward solve L^T x = y (fresh each step, as reference) ----
#pragma unroll
    for (int i = SPAR - 1; i >= 0; --i)
      if (i <= s) {
        float a = ysel[i];
#pragma unroll
        for (int t = 0; t < SPAR; ++t)
          if (t > i && t <= s) a = fmaf(-Lm[t][i], coefF[t], a);
        coefF[i] = a * invL[i];
      }

    // pin the fetched row so the compiler cannot rematerialize the loads;
    // the implied waitcnt lands HERE (after chol/solve), not at fetch time
    if (s < SPAR - 1) {
#pragma unroll
      for (int j = 0; j < 16; ++j) asm volatile("" : "+v"(rows[s][j]));
    }
  }

  // ---- outputs: recon [n][64], I [n][8], coeffs [n][8] ----
  double r = 0.0;
#pragma unroll
  for (int i = 0; i < SPAR; ++i) {
    float dv = DTW ? Dt[(size_t)selI[i] * DIM + lane]
                   : D[(size_t)lane * NATOM + selI[i]];
    r += (double)coefF[i] * (double)dv;
  }
  out[(size_t)n * DIM + lane] = (float)r;

  float fi = 0.f, fc = 0.f;
#pragma unroll
  for (int i = 0; i < SPAR; ++i)
    if (lane == i) { fi = (float)selI[i]; fc = coefF[i]; }
  if (lane < SPAR) {
    out[(size_t)NPIX * DIM + (size_t)n * SPAR + lane] = fi;
    out[(size_t)NPIX * DIM + (size_t)NPIX * SPAR + (size_t)n * SPAR + lane] = fc;
  }
}

extern "C" void kernel_launch(void* const* d_in, const int* in_sizes, int n_in,
                              void* d_out, int out_size, void* d_ws,
                              size_t ws_size, hipStream_t stream) {
  const float* X = (const float*)d_in[0];  // [64, 16384]
  const float* D = (const float*)d_in[1];  // [64, 1024]
  float* out = (float*)d_out;              // [recon | I | coeffs] as fp32
  float* G = (float*)d_ws;
  const size_t needG = (size_t)NATOM * NATOM * sizeof(float);
  const size_t needHB = needG + (size_t)NPIX * NATOM * sizeof(float);
  const size_t needDt = needHB + (size_t)NATOM * DIM * sizeof(float);

  k_gram<<<dim3(NATOM), dim3(256), 0, stream>>>(D, G);

  if (ws_size >= needDt) {
    float* HB = G + (size_t)NATOM * NATOM;
    float* Dt = HB + (size_t)NPIX * NATOM;
    k_tr<<<dim3(NATOM * DIM / 256), dim3(256), 0, stream>>>(D, Dt);
    k_hbar<<<dim3(NPIX / 128, NATOM / 128), dim3(256), 0, stream>>>(X, D, HB);
    k_omp<true, true><<<dim3(NPIX / 4), dim3(256), 0, stream>>>(HB, X, D, Dt, G, out);
  } else if (ws_size >= needHB) {
    float* HB = G + (size_t)NATOM * NATOM;
    k_hbar<<<dim3(NPIX / 128, NATOM / 128), dim3(256), 0, stream>>>(X, D, HB);
    k_omp<true, false><<<dim3(NPIX / 4), dim3(256), 0, stream>>>(HB, X, D, nullptr, G, out);
  } else {
    k_omp<false, false><<<dim3(NPIX / 4), dim3(256), 0, stream>>>(nullptr, X, D, nullptr, G, out);
  }
}

// Round 5
// 144.201 us; speedup vs baseline: 2.2702x; 1.3265x over previous
//
#include <hip/hip_runtime.h>
#include <cmath>

#define NPIX 16384
#define NATOM 1024
#define DIM 64
#define SPAR 8

// ---------------------------------------------------------------------------
// Fused pre-pass, grid-partitioned:
//   blocks [0, 1024):    G row k1 = D^T D + 1e-4 I (fp64 acc) ; Dt row k1
//   blocks [1024, 2048): HB 128n x 128k tile (fp32, 8x8/thread)
// ---------------------------------------------------------------------------
__global__ __launch_bounds__(256) void k_pre(const float* __restrict__ X,
                                             const float* __restrict__ D,
                                             float* __restrict__ G,
                                             float* __restrict__ Dt,
                                             float* __restrict__ HB) {
  __shared__ float smem[2 * DIM * 128];  // 64 KiB
  if (blockIdx.x < NATOM) {
    const int k1 = blockIdx.x;
    float* d1 = smem;
    if (threadIdx.x < DIM) {
      float v = D[(size_t)threadIdx.x * NATOM + k1];
      d1[threadIdx.x] = v;
      Dt[(size_t)k1 * DIM + threadIdx.x] = v;  // transpose for recon gather
    }
    __syncthreads();
    for (int k2 = threadIdx.x; k2 < NATOM; k2 += 256) {
      double acc = 0.0;
#pragma unroll
      for (int d = 0; d < DIM; ++d)
        acc += (double)d1[d] * (double)D[(size_t)d * NATOM + k2];
      float g = (float)acc;
      if (k2 == k1) g += 1e-4f;
      G[(size_t)k1 * NATOM + k2] = g;
    }
  } else {
    const int bx = blockIdx.x - NATOM;
    const int n0 = (bx & 127) * 128, k0 = (bx >> 7) * 128;
    float(*sX)[128] = (float(*)[128])smem;
    float(*sD)[128] = (float(*)[128])(smem + DIM * 128);
    for (int i = threadIdx.x; i < DIM * 32; i += 256) {
      int d = i >> 5, c4 = (i & 31) * 4;
      *reinterpret_cast<float4*>(&sX[d][c4]) =
          *reinterpret_cast<const float4*>(&X[(size_t)d * NPIX + n0 + c4]);
      *reinterpret_cast<float4*>(&sD[d][c4]) =
          *reinterpret_cast<const float4*>(&D[(size_t)d * NATOM + k0 + c4]);
    }
    __syncthreads();
    const int nl = (threadIdx.x & 15) * 8;
    const int kl = (threadIdx.x >> 4) * 8;
    float acc[8][8];
#pragma unroll
    for (int i = 0; i < 8; ++i)
#pragma unroll
      for (int j = 0; j < 8; ++j) acc[i][j] = 0.f;
#pragma unroll 4
    for (int d = 0; d < DIM; ++d) {
      float xv[8], dv[8];
      *reinterpret_cast<float4*>(&xv[0]) = *reinterpret_cast<float4*>(&sX[d][nl]);
      *reinterpret_cast<float4*>(&xv[4]) = *reinterpret_cast<float4*>(&sX[d][nl + 4]);
      *reinterpret_cast<float4*>(&dv[0]) = *reinterpret_cast<float4*>(&sD[d][kl]);
      *reinterpret_cast<float4*>(&dv[4]) = *reinterpret_cast<float4*>(&sD[d][kl + 4]);
#pragma unroll
      for (int i = 0; i < 8; ++i)
#pragma unroll
        for (int j = 0; j < 8; ++j) acc[i][j] = fmaf(xv[i], dv[j], acc[i][j]);
    }
#pragma unroll
    for (int i = 0; i < 8; ++i)
#pragma unroll
      for (int j = 0; j < 2; ++j)
        *reinterpret_cast<float4*>(
            &HB[(size_t)(n0 + nl + i) * NATOM + k0 + kl + j * 4]) =
            *reinterpret_cast<float4*>(&acc[i][j * 4]);
  }
}

// Standalone fallbacks (smaller-workspace paths)
__global__ __launch_bounds__(256) void k_gram(const float* __restrict__ D,
                                              float* __restrict__ G) {
  int k1 = blockIdx.x;
  __shared__ float d1[DIM];
  if (threadIdx.x < DIM) d1[threadIdx.x] = D[(size_t)threadIdx.x * NATOM + k1];
  __syncthreads();
  for (int k2 = threadIdx.x; k2 < NATOM; k2 += 256) {
    double acc = 0.0;
#pragma unroll
    for (int d = 0; d < DIM; ++d)
      acc += (double)d1[d] * (double)D[(size_t)d * NATOM + k2];
    float g = (float)acc;
    if (k2 == k1) g += 1e-4f;
    G[(size_t)k1 * NATOM + k2] = g;
  }
}
__global__ __launch_bounds__(256) void k_hbar(const float* __restrict__ X,
                                              const float* __restrict__ D,
                                              float* __restrict__ HB) {
  // thin wrapper over the same math as k_pre's else-branch, 128x128 tile
  __shared__ float sX[DIM][128];
  __shared__ float sD[DIM][128];
  const int n0 = blockIdx.x * 128, k0 = blockIdx.y * 128;
  for (int i = threadIdx.x; i < DIM * 32; i += 256) {
    int d = i >> 5, c4 = (i & 31) * 4;
    *reinterpret_cast<float4*>(&sX[d][c4]) =
        *reinterpret_cast<const float4*>(&X[(size_t)d * NPIX + n0 + c4]);
    *reinterpret_cast<float4*>(&sD[d][c4]) =
        *reinterpret_cast<const float4*>(&D[(size_t)d * NATOM + k0 + c4]);
  }
  __syncthreads();
  const int nl = (threadIdx.x & 15) * 8;
  const int kl = (threadIdx.x >> 4) * 8;
  float acc[8][8];
#pragma unroll
  for (int i = 0; i < 8; ++i)
#pragma unroll
    for (int j = 0; j < 8; ++j) acc[i][j] = 0.f;
#pragma unroll 4
  for (int d = 0; d < DIM; ++d) {
    float xv[8], dv[8];
    *reinterpret_cast<float4*>(&xv[0]) = *reinterpret_cast<float4*>(&sX[d][nl]);
    *reinterpret_cast<float4*>(&xv[4]) = *reinterpret_cast<float4*>(&sX[d][nl + 4]);
    *reinterpret_cast<float4*>(&dv[0]) = *reinterpret_cast<float4*>(&sD[d][kl]);
    *reinterpret_cast<float4*>(&dv[4]) = *reinterpret_cast<float4*>(&sD[d][kl + 4]);
#pragma unroll
    for (int i = 0; i < 8; ++i)
#pragma unroll
      for (int j = 0; j < 8; ++j) acc[i][j] = fmaf(xv[i], dv[j], acc[i][j]);
  }
#pragma unroll
  for (int i = 0; i < 8; ++i)
#pragma unroll
    for (int j = 0; j < 2; ++j)
      *reinterpret_cast<float4*>(
          &HB[(size_t)(n0 + nl + i) * NATOM + k0 + kl + j * 4]) =
          *reinterpret_cast<float4*>(&acc[i][j * 4]);
}

// ---------------------------------------------------------------------------
// Batched OMP: one 64-lane wave per pixel. Lane owns k = lane*16+j, j=0..15
// (consecutive atoms -> all G-row / HB traffic is dwordx4, 64B/lane).
// Argmax: M = wave-max(score) via exact f32 max tree+butterfly, then index =
// wave-min(score==M ? idx : 1024) -> first-occurrence semantics, identical
// to np.argmax. h / chol / solve numerics identical to the passing rounds.
// ---------------------------------------------------------------------------
template <bool HBWS, bool DTW>
__global__ __launch_bounds__(256, 2) void k_omp(const float* __restrict__ HB,
                                                const float* __restrict__ X,
                                                const float* __restrict__ D,
                                                const float* __restrict__ Dt,
                                                const float* __restrict__ G,
                                                float* __restrict__ out) {
  const int lane = threadIdx.x & 63;
  const int n = blockIdx.x * 4 + (threadIdx.x >> 6);

  float hb[16];
  if (HBWS) {
#pragma unroll
    for (int q = 0; q < 4; ++q) {
      float4 v = *reinterpret_cast<const float4*>(
          &HB[(size_t)n * NATOM + lane * 16 + q * 4]);
      hb[q * 4 + 0] = v.x; hb[q * 4 + 1] = v.y;
      hb[q * 4 + 2] = v.z; hb[q * 4 + 3] = v.w;
    }
  } else {
    double a[16];
#pragma unroll
    for (int j = 0; j < 16; ++j) a[j] = 0.0;
    for (int d = 0; d < DIM; ++d) {
      float xd = X[(size_t)d * NPIX + n];
#pragma unroll
      for (int j = 0; j < 16; ++j)
        a[j] += (double)xd * (double)D[(size_t)d * NATOM + lane * 16 + j];
    }
#pragma unroll
    for (int j = 0; j < 16; ++j) hb[j] = (float)a[j];
  }
#pragma unroll
  for (int j = 0; j < 16; ++j) asm volatile("" : "+v"(hb[j]));

  unsigned mask = 0;  // bit j: atom (lane*16+j) already selected
  int selI[SPAR];
  float rows[SPAR - 1][16];  // rows[i][j] = G[selI[i]][lane*16+j]
  float Lm[SPAR][SPAR], invL[SPAR], ysel[SPAR], coefF[SPAR];

#pragma unroll 8
  for (int s = 0; s < SPAR; ++s) {
    // ---- scores ----
    float sc[16];
#pragma unroll
    for (int j = 0; j < 16; ++j) {
      float h = hb[j];
#pragma unroll
      for (int i = 0; i < SPAR - 1; ++i)
        if (i < s) h = fmaf(-coefF[i], rows[i][j], h);
      sc[j] = ((mask >> j) & 1u) ? -1.0f : fabsf(h);
    }
    // ---- wave max (exact f32) ----
    float m0 = fmaxf(fmaxf(fmaxf(sc[0], sc[1]), sc[2]), sc[3]);
    float m1 = fmaxf(fmaxf(fmaxf(sc[4], sc[5]), sc[6]), sc[7]);
    float m2 = fmaxf(fmaxf(fmaxf(sc[8], sc[9]), sc[10]), sc[11]);
    float m3 = fmaxf(fmaxf(fmaxf(sc[12], sc[13]), sc[14]), sc[15]);
    float M = fmaxf(fmaxf(m0, m1), fmaxf(m2, m3));
#pragma unroll
    for (int off = 1; off <= 32; off <<= 1) M = fmaxf(M, __shfl_xor(M, off));
    // ---- min index among score==M (first occurrence, as np.argmax) ----
    unsigned sel = NATOM;
#pragma unroll
    for (int j = 0; j < 16; ++j) {
      unsigned idx = (unsigned)(lane * 16 + j);
      unsigned cand = (sc[j] == M) ? idx : (unsigned)NATOM;
      sel = sel < cand ? sel : cand;
    }
#pragma unroll
    for (int off = 1; off <= 32; off <<= 1) {
      unsigned o = __shfl_xor(sel, off);
      sel = sel < o ? sel : o;
    }
    const int bk = __builtin_amdgcn_readfirstlane((int)sel);  // wave-uniform
    selI[s] = bk;
    const int bl = bk >> 4, bj = bk & 15;
    if (lane == bl) mask |= (1u << bj);

    // gather h_bar[bk] (compile-time-indexed select + shfl)
    float v = 0.f;
#pragma unroll
    for (int j = 0; j < 16; ++j)
      if (j == bj) v = hb[j];
    const float hbs = __shfl(v, bl);

    // issue new-row fetch (dwordx4 x4); completes during chol/solve below
    if (s < SPAR - 1) {
#pragma unroll
      for (int q = 0; q < 4; ++q) {
        float4 rv = *reinterpret_cast<const float4*>(
            &G[(size_t)bk * NATOM + lane * 16 + q * 4]);
        rows[s][q * 4 + 0] = rv.x; rows[s][q * 4 + 1] = rv.y;
        rows[s][q * 4 + 2] = rv.z; rows[s][q * 4 + 3] = rv.w;
      }
    }

    // ---- Cholesky update: L_{s+1} = [[L, 0], [w^T, corner]] ----
    const float diag = G[(size_t)bk * NATOM + bk];  // uniform (scalar) load
    float w[SPAR];
    float sq = 0.f;
#pragma unroll
    for (int i = 0; i < SPAR; ++i)
      if (i < s) {
        float a = G[(size_t)selI[i] * NATOM + bk];  // uniform (scalar) load
#pragma unroll
        for (int t = 0; t < SPAR; ++t)
          if (t < i) a = fmaf(-Lm[i][t], w[t], a);
        w[i] = a * invL[i];
        sq += w[i] * w[i];
        Lm[s][i] = w[i];
      }
    float cc = diag - sq;
    if (cc < 1e-6f) cc = 1e-6f;  // jnp.clip(..., CHOL_EPS)
    Lm[s][s] = sqrtf(cc);
    invL[s] = 1.0f / Lm[s][s];

    // ---- y_s (incremental forward solve) ----
    {
      float a = hbs;
#pragma unroll
      for (int t = 0; t < SPAR; ++t)
        if (t < s) a = fmaf(-Lm[s][t], ysel[t], a);
      ysel[s] = a * invL[s];
    }
    // ---- coef: backward solve L^T x = y ----
#pragma unroll
    for (int i = SPAR - 1; i >= 0; --i)
      if (i <= s) {
        float a = ysel[i];
#pragma unroll
        for (int t = 0; t < SPAR; ++t)
          if (t > i && t <= s) a = fmaf(-Lm[t][i], coefF[t], a);
        coefF[i] = a * invL[i];
      }

    // pin the fetched row: forces residency; waitcnt lands here (post-solve)
    if (s < SPAR - 1) {
#pragma unroll
      for (int j = 0; j < 16; ++j) asm volatile("" : "+v"(rows[s][j]));
    }
  }

  // ---- outputs: recon [n][64], I [n][8], coeffs [n][8] ----
  double r = 0.0;
#pragma unroll
  for (int i = 0; i < SPAR; ++i) {
    float dv = DTW ? Dt[(size_t)selI[i] * DIM + lane]
                   : D[(size_t)lane * NATOM + selI[i]];
    r += (double)coefF[i] * (double)dv;
  }
  out[(size_t)n * DIM + lane] = (float)r;

  float fi = 0.f, fc = 0.f;
#pragma unroll
  for (int i = 0; i < SPAR; ++i)
    if (lane == i) { fi = (float)selI[i]; fc = coefF[i]; }
  if (lane < SPAR) {
    out[(size_t)NPIX * DIM + (size_t)n * SPAR + lane] = fi;
    out[(size_t)NPIX * DIM + (size_t)NPIX * SPAR + (size_t)n * SPAR + lane] = fc;
  }
}

extern "C" void kernel_launch(void* const* d_in, const int* in_sizes, int n_in,
                              void* d_out, int out_size, void* d_ws,
                              size_t ws_size, hipStream_t stream) {
  const float* X = (const float*)d_in[0];  // [64, 16384]
  const float* D = (const float*)d_in[1];  // [64, 1024]
  float* out = (float*)d_out;              // [recon | I | coeffs] as fp32
  float* G = (float*)d_ws;
  const size_t needG = (size_t)NATOM * NATOM * sizeof(float);
  const size_t needHB = needG + (size_t)NPIX * NATOM * sizeof(float);
  const size_t needDt = needHB + (size_t)NATOM * DIM * sizeof(float);

  if (ws_size >= needDt) {
    float* HB = G + (size_t)NATOM * NATOM;
    float* Dt = HB + (size_t)NPIX * NATOM;
    k_pre<<<dim3(2 * NATOM), dim3(256), 0, stream>>>(X, D, G, Dt, HB);
    k_omp<true, true><<<dim3(NPIX / 4), dim3(256), 0, stream>>>(HB, X, D, Dt, G, out);
  } else if (ws_size >= needHB) {
    float* HB = G + (size_t)NATOM * NATOM;
    k_gram<<<dim3(NATOM), dim3(256), 0, stream>>>(D, G);
    k_hbar<<<dim3(NPIX / 128, NATOM / 128), dim3(256), 0, stream>>>(X, D, HB);
    k_omp<true, false><<<dim3(NPIX / 4), dim3(256), 0, stream>>>(HB, X, D, nullptr, G, out);
  } else {
    k_gram<<<dim3(NATOM), dim3(256), 0, stream>>>(D, G);
    k_omp<false, false><<<dim3(NPIX / 4), dim3(256), 0, stream>>>(nullptr, X, D, nullptr, G, out);
  }
}